// Round 8
// baseline (1541.872 us; speedup 1.0000x reference)
//
#include <hip/hip_runtime.h>
#include <math.h>

#define NN 20000   // nodes
#define NE 320000  // edges (without self-loops)
#define TT 8       // timesteps
#define D1 256     // H*F layer-1 width
#define CD 32      // layer-2 width == LSTM hidden

// ---------------- CSR build (once per launch; edges identical across t) ----------------

__global__ __launch_bounds__(256) void k_deg(const int* __restrict__ dst, int* __restrict__ deg) {
  int e = blockIdx.x * 256 + threadIdx.x;
  if (e < NE) atomicAdd(&deg[dst[e]], 1);
}

__global__ __launch_bounds__(1024) void k_scan(const int* __restrict__ deg,
                                               int* __restrict__ rowptr, int* __restrict__ fill) {
  __shared__ int sd[1024];
  __shared__ int carry_s;
  int tid = threadIdx.x;
  if (tid == 0) { carry_s = 0; rowptr[0] = 0; }
  __syncthreads();
  for (int base = 0; base < NN; base += 1024) {
    int i = base + tid;
    int v = (i < NN) ? deg[i] : 0;
    sd[tid] = v;
    __syncthreads();
    for (int off = 1; off < 1024; off <<= 1) {
      int t = (tid >= off) ? sd[tid - off] : 0;
      __syncthreads();
      sd[tid] += t;
      __syncthreads();
    }
    int incl = sd[tid];
    int carry = carry_s;
    if (i < NN) { rowptr[i + 1] = carry + incl; fill[i] = carry + incl - v; }
    __syncthreads();
    if (tid == 1023) carry_s = carry + sd[1023];
    __syncthreads();
  }
}

__global__ __launch_bounds__(256) void k_fill(const int* __restrict__ src, const int* __restrict__ dst,
                                              int* __restrict__ fill, int* __restrict__ csr) {
  int e = blockIdx.x * 256 + threadIdx.x;
  if (e < NE) {
    int pos = atomicAdd(&fill[dst[e]], 1);
    csr[pos] = src[e];
  }
}

// ---------------- one-time: folded attention vectors + weight transposes --------------------

__global__ __launch_bounds__(256) void k_prew(const float* __restrict__ W1,
    const float* __restrict__ as1, const float* __restrict__ ad1,
    const float* __restrict__ W2,
    float* __restrict__ wsrc, float* __restrict__ wdst,
    float* __restrict__ W1T, float* __restrict__ W2T) {
  int tid = threadIdx.x;
  int k = tid >> 3, h = tid & 7;
  float s = 0.f, d = 0.f;
  #pragma unroll
  for (int f = 0; f < 32; ++f) {
    float wv = W1[k * D1 + h * 32 + f];
    s = fmaf(wv, as1[h * 32 + f], s);
    d = fmaf(wv, ad1[h * 32 + f], d);
  }
  wsrc[k * 8 + h] = s;
  wdst[k * 8 + h] = d;
  for (int i = tid; i < D1 * 32; i += 256) {
    int j = i >> 5, kk = i & 31;
    W1T[i] = W1[kk * D1 + j];          // W1T[j*32+kk]
  }
  for (int i = tid; i < 32 * D1; i += 256) {
    int f = i >> 8, kk = i & 255;
    W2T[i] = W2[kk * CD + f];          // W2T[f*256+kk]
  }
}

// ---------------- logits for all t: als/ald = x @ w~ ; t = blockIdx.x & 7 -------------------

__global__ __launch_bounds__(256) void k_logits8(const float* __restrict__ x,
    const float* __restrict__ wsrc, const float* __restrict__ wdst,
    float* __restrict__ als, float* __restrict__ ald) {
  __shared__ float xs[32 * 33];
  __shared__ float wsr[256], wdr[256];
  int tid = threadIdx.x;
  int t = blockIdx.x & 7;
  int n0 = (blockIdx.x >> 3) * 32;
  const float* xt = x + (size_t)t * NN * 32;
  int nl = tid >> 3, h = tid & 7;
  for (int i = tid; i < 1024; i += 256) {
    int g = i >> 5, k = i & 31;
    xs[g * 33 + k] = xt[n0 * 32 + i];
  }
  wsr[tid] = wsrc[tid];
  wdr[tid] = wdst[tid];
  __syncthreads();
  const float* xr = xs + nl * 33;
  float as = 0.f, ad = 0.f;
  #pragma unroll
  for (int k = 0; k < 32; ++k) {
    float xv = xr[k];
    as = fmaf(xv, wsr[k * 8 + h], as);
    ad = fmaf(xv, wdr[k * 8 + h], ad);
  }
  als[(size_t)t * NN * 8 + n0 * 8 + tid] = as;
  ald[(size_t)t * NN * 8 + n0 * 8 + tid] = ad;
}

// ---------------- FUSED layer-1: gather + per-head W1 matvec + ReLU + W2 + logits ----------
// Lane (t,h) ends the edge loop holding EXACTLY aggx[t][n][h][0:32] in acc[] -- each head's
// 256-wide projection uses only its own head's 32-float aggregate (W1 is input-dim 32), so
// the whole k_post GEMM chain runs as a register epilogue. Eliminates the 328 MB aggx
// round-trip and the k_post kernel. Weights (8 KB) stream from L1/L2. Cross-h reduction via
// in-wave butterfly (lane = t*8+h; xor on bits 0..2 stays inside the t-group). No LDS.

__global__ __launch_bounds__(256, 1) void k_gat1(const float* __restrict__ x,
    const float* __restrict__ als, const float* __restrict__ ald,
    const int* __restrict__ rowptr, const int* __restrict__ csr,
    const float* __restrict__ W1T, const float* __restrict__ b1,
    const float* __restrict__ W2T, const float* __restrict__ as2,
    const float* __restrict__ ad2,
    float* __restrict__ h2, float* __restrict__ al2s, float* __restrict__ al2d) {
  int tid = threadIdx.x;
  int wv = tid >> 6, lane = tid & 63;
  int t = lane >> 3, h = lane & 7;
  int n = blockIdx.x * 4 + wv;
  const float* alst = als + (size_t)t * NN * 8 + h;           // + s*8 per edge
  float adv = ald[(size_t)t * NN * 8 + (size_t)n * 8 + h];
  const float4* x4t = (const float4*)(x + (size_t)t * NN * 32);
  float4 acc[8];
  #pragma unroll
  for (int q = 0; q < 8; ++q) acc[q] = make_float4(0.f, 0.f, 0.f, 0.f);
  float den = 0.f;
  int beg = rowptr[n], end = rowptr[n + 1];
  // virtual list [beg, end]: edges then self-loop at position `end`
  int v = beg;
  for (; v + 1 <= end; v += 2) {
    int s0 = csr[v];                              // v < end guaranteed here
    int s1 = (v + 1 < end) ? csr[v + 1] : n;
    float a0 = alst[(size_t)s0 * 8] + adv;
    float a1 = alst[(size_t)s1 * 8] + adv;
    const float4* xr0 = x4t + (size_t)s0 * 8;
    const float4* xr1 = x4t + (size_t)s1 * 8;
    a0 = fmaxf(a0, 0.2f * a0);
    a1 = fmaxf(a1, 0.2f * a1);
    float e0 = __expf(a0), e1 = __expf(a1);
    float4 u0 = xr0[0], u1 = xr0[1], u2 = xr0[2], u3 = xr0[3];
    float4 u4 = xr0[4], u5 = xr0[5], u6 = xr0[6], u7 = xr0[7];
    float4 w0 = xr1[0], w1 = xr1[1], w2 = xr1[2], w3 = xr1[3];
    float4 w4 = xr1[4], w5 = xr1[5], w6 = xr1[6], w7 = xr1[7];
    acc[0].x = fmaf(e1, w0.x, fmaf(e0, u0.x, acc[0].x));
    acc[0].y = fmaf(e1, w0.y, fmaf(e0, u0.y, acc[0].y));
    acc[0].z = fmaf(e1, w0.z, fmaf(e0, u0.z, acc[0].z));
    acc[0].w = fmaf(e1, w0.w, fmaf(e0, u0.w, acc[0].w));
    acc[1].x = fmaf(e1, w1.x, fmaf(e0, u1.x, acc[1].x));
    acc[1].y = fmaf(e1, w1.y, fmaf(e0, u1.y, acc[1].y));
    acc[1].z = fmaf(e1, w1.z, fmaf(e0, u1.z, acc[1].z));
    acc[1].w = fmaf(e1, w1.w, fmaf(e0, u1.w, acc[1].w));
    acc[2].x = fmaf(e1, w2.x, fmaf(e0, u2.x, acc[2].x));
    acc[2].y = fmaf(e1, w2.y, fmaf(e0, u2.y, acc[2].y));
    acc[2].z = fmaf(e1, w2.z, fmaf(e0, u2.z, acc[2].z));
    acc[2].w = fmaf(e1, w2.w, fmaf(e0, u2.w, acc[2].w));
    acc[3].x = fmaf(e1, w3.x, fmaf(e0, u3.x, acc[3].x));
    acc[3].y = fmaf(e1, w3.y, fmaf(e0, u3.y, acc[3].y));
    acc[3].z = fmaf(e1, w3.z, fmaf(e0, u3.z, acc[3].z));
    acc[3].w = fmaf(e1, w3.w, fmaf(e0, u3.w, acc[3].w));
    acc[4].x = fmaf(e1, w4.x, fmaf(e0, u4.x, acc[4].x));
    acc[4].y = fmaf(e1, w4.y, fmaf(e0, u4.y, acc[4].y));
    acc[4].z = fmaf(e1, w4.z, fmaf(e0, u4.z, acc[4].z));
    acc[4].w = fmaf(e1, w4.w, fmaf(e0, u4.w, acc[4].w));
    acc[5].x = fmaf(e1, w5.x, fmaf(e0, u5.x, acc[5].x));
    acc[5].y = fmaf(e1, w5.y, fmaf(e0, u5.y, acc[5].y));
    acc[5].z = fmaf(e1, w5.z, fmaf(e0, u5.z, acc[5].z));
    acc[5].w = fmaf(e1, w5.w, fmaf(e0, u5.w, acc[5].w));
    acc[6].x = fmaf(e1, w6.x, fmaf(e0, u6.x, acc[6].x));
    acc[6].y = fmaf(e1, w6.y, fmaf(e0, u6.y, acc[6].y));
    acc[6].z = fmaf(e1, w6.z, fmaf(e0, u6.z, acc[6].z));
    acc[6].w = fmaf(e1, w6.w, fmaf(e0, u6.w, acc[6].w));
    acc[7].x = fmaf(e1, w7.x, fmaf(e0, u7.x, acc[7].x));
    acc[7].y = fmaf(e1, w7.y, fmaf(e0, u7.y, acc[7].y));
    acc[7].z = fmaf(e1, w7.z, fmaf(e0, u7.z, acc[7].z));
    acc[7].w = fmaf(e1, w7.w, fmaf(e0, u7.w, acc[7].w));
    den += e0 + e1;
  }
  if (v <= end) {                                 // 1 leftover (edge or self-loop)
    int s = (v < end) ? csr[v] : n;
    float a = alst[(size_t)s * 8] + adv;
    a = fmaxf(a, 0.2f * a);
    float e = __expf(a);
    const float4* xr = x4t + (size_t)s * 8;
    #pragma unroll
    for (int q = 0; q < 8; ++q) {
      float4 xv = xr[q];
      acc[q].x = fmaf(e, xv.x, acc[q].x);
      acc[q].y = fmaf(e, xv.y, acc[q].y);
      acc[q].z = fmaf(e, xv.z, acc[q].z);
      acc[q].w = fmaf(e, xv.w, acc[q].w);
    }
    den += e;
  }

  // ===== fused dense epilogue (replaces k_post) =====
  float invd = 1.f / den;

  // phase A: rel[f] = relu( dot32(acc, W1T row h*32+f) * invd + b1[h*32+f] ), f = 0..31
  const float4* w1row = (const float4*)(W1T + (size_t)(h * 32) * 32);  // 8 quads per row
  const float4* b1q = ((const float4*)b1) + h * 8;
  float4 rel[8];
  #pragma unroll
  for (int fq = 0; fq < 8; ++fq) {
    const float4* r0 = w1row + (fq * 4 + 0) * 8;
    const float4* r1 = w1row + (fq * 4 + 1) * 8;
    const float4* r2 = w1row + (fq * 4 + 2) * 8;
    const float4* r3 = w1row + (fq * 4 + 3) * 8;
    float s0 = 0.f, s1 = 0.f, s2 = 0.f, s3 = 0.f;
    #pragma unroll
    for (int k4 = 0; k4 < 8; ++k4) {
      float4 av = acc[k4];
      float4 wa = r0[k4], wb = r1[k4], wc = r2[k4], wd = r3[k4];
      s0 = fmaf(av.x, wa.x, fmaf(av.y, wa.y, fmaf(av.z, wa.z, fmaf(av.w, wa.w, s0))));
      s1 = fmaf(av.x, wb.x, fmaf(av.y, wb.y, fmaf(av.z, wb.z, fmaf(av.w, wb.w, s1))));
      s2 = fmaf(av.x, wc.x, fmaf(av.y, wc.y, fmaf(av.z, wc.z, fmaf(av.w, wc.w, s2))));
      s3 = fmaf(av.x, wd.x, fmaf(av.y, wd.y, fmaf(av.z, wd.z, fmaf(av.w, wd.w, s3))));
    }
    float4 bq = b1q[fq];
    rel[fq].x = fmaxf(fmaf(s0, invd, bq.x), 0.f);
    rel[fq].y = fmaxf(fmaf(s1, invd, bq.y), 0.f);
    rel[fq].z = fmaxf(fmaf(s2, invd, bq.z), 0.f);
    rel[fq].w = fmaxf(fmaf(s3, invd, bq.w), 0.f);
  }

  // phase B: per-lane partial p[f] = sum_{jj in h-block} rel[jj] * W2T[f*256 + h*32 + jj]
  float4 p[8];
  #pragma unroll
  for (int fq = 0; fq < 8; ++fq) {
    const float4* r0 = (const float4*)(W2T + (size_t)(fq * 4 + 0) * 256 + h * 32);
    const float4* r1 = (const float4*)(W2T + (size_t)(fq * 4 + 1) * 256 + h * 32);
    const float4* r2 = (const float4*)(W2T + (size_t)(fq * 4 + 2) * 256 + h * 32);
    const float4* r3 = (const float4*)(W2T + (size_t)(fq * 4 + 3) * 256 + h * 32);
    float s0 = 0.f, s1 = 0.f, s2 = 0.f, s3 = 0.f;
    #pragma unroll
    for (int j4 = 0; j4 < 8; ++j4) {
      float4 rv = rel[j4];
      float4 wa = r0[j4], wb = r1[j4], wc = r2[j4], wd = r3[j4];
      s0 = fmaf(rv.x, wa.x, fmaf(rv.y, wa.y, fmaf(rv.z, wa.z, fmaf(rv.w, wa.w, s0))));
      s1 = fmaf(rv.x, wb.x, fmaf(rv.y, wb.y, fmaf(rv.z, wb.z, fmaf(rv.w, wb.w, s1))));
      s2 = fmaf(rv.x, wc.x, fmaf(rv.y, wc.y, fmaf(rv.z, wc.z, fmaf(rv.w, wc.w, s2))));
      s3 = fmaf(rv.x, wd.x, fmaf(rv.y, wd.y, fmaf(rv.z, wd.z, fmaf(rv.w, wd.w, s3))));
    }
    p[fq].x = s0; p[fq].y = s1; p[fq].z = s2; p[fq].w = s3;
  }

  // cross-h butterfly within each t-group (lane = t*8+h; xor bits 0..2 flip h only)
  #pragma unroll
  for (int m = 1; m < 8; m <<= 1) {
    #pragma unroll
    for (int fq = 0; fq < 8; ++fq) {
      p[fq].x += __shfl_xor(p[fq].x, m, 64);
      p[fq].y += __shfl_xor(p[fq].y, m, 64);
      p[fq].z += __shfl_xor(p[fq].z, m, 64);
      p[fq].w += __shfl_xor(p[fq].w, m, 64);
    }
  }

  // h2 write: lane h writes quad h (static-index ladder -- no runtime register indexing)
  float4 mine = p[0];
  #pragma unroll
  for (int fq = 1; fq < 8; ++fq) if (fq == h) mine = p[fq];
  ((float4*)(h2 + ((size_t)t * NN + n) * 32))[h] = mine;

  // layer-2 logits (p identical on all h-lanes after reduction; h==0 stores)
  const float4* as24 = (const float4*)as2;
  const float4* ad24 = (const float4*)ad2;
  float vs = 0.f, vd = 0.f;
  #pragma unroll
  for (int fq = 0; fq < 8; ++fq) {
    float4 pv = p[fq], a = as24[fq], d = ad24[fq];
    vs = fmaf(pv.x, a.x, fmaf(pv.y, a.y, fmaf(pv.z, a.z, fmaf(pv.w, a.w, vs))));
    vd = fmaf(pv.x, d.x, fmaf(pv.y, d.y, fmaf(pv.z, d.z, fmaf(pv.w, d.w, vd))));
  }
  if (h == 0) {
    al2s[(size_t)t * NN + n] = vs;
    al2d[(size_t)t * NN + n] = vd;
  }
}

// ---------------- layer-2 aggregation, ALL t in one wave: lane=(t, f-quad), 2-edge unroll ---

__global__ __launch_bounds__(256, 4) void k_agg2(const float* __restrict__ h2,
    const float* __restrict__ al2s, const float* __restrict__ al2d,
    const int* __restrict__ rowptr, const int* __restrict__ csr,
    const float* __restrict__ b2, float* __restrict__ out) {
  int tid = threadIdx.x;
  int wv = tid >> 6, lane = tid & 63;
  int t = lane >> 3, p = lane & 7;
  int n = blockIdx.x * 4 + wv;
  const float* alst = al2s + (size_t)t * NN;
  float adv = al2d[(size_t)t * NN + n];
  const float4* h24 = (const float4*)h2 + (size_t)t * NN * 8 + p;
  float4 b4 = ((const float4*)b2)[p];
  float4 acc = make_float4(0.f, 0.f, 0.f, 0.f);
  float den = 0.f;
  int beg = rowptr[n], end = rowptr[n + 1];
  int v = beg;
  for (; v + 1 <= end; v += 2) {
    int s0 = csr[v];
    int s1 = (v + 1 < end) ? csr[v + 1] : n;
    float a0 = alst[s0] + adv;
    float a1 = alst[s1] + adv;
    float4 u = h24[(size_t)s0 * 8];
    float4 w = h24[(size_t)s1 * 8];
    a0 = fmaxf(a0, 0.2f * a0);
    a1 = fmaxf(a1, 0.2f * a1);
    float e0 = __expf(a0), e1 = __expf(a1);
    acc.x = fmaf(e1, w.x, fmaf(e0, u.x, acc.x));
    acc.y = fmaf(e1, w.y, fmaf(e0, u.y, acc.y));
    acc.z = fmaf(e1, w.z, fmaf(e0, u.z, acc.z));
    acc.w = fmaf(e1, w.w, fmaf(e0, u.w, acc.w));
    den += e0 + e1;
  }
  if (v <= end) {
    int s = (v < end) ? csr[v] : n;
    float a = alst[s] + adv;
    a = fmaxf(a, 0.2f * a);
    float e = __expf(a);
    float4 u = h24[(size_t)s * 8];
    acc.x = fmaf(e, u.x, acc.x);
    acc.y = fmaf(e, u.y, acc.y);
    acc.z = fmaf(e, u.z, acc.z);
    acc.w = fmaf(e, u.w, acc.w);
    den += e;
  }
  float inv = 1.f / den;
  float4 o;
  o.x = fmaf(acc.x, inv, b4.x);
  o.y = fmaf(acc.y, inv, b4.y);
  o.z = fmaf(acc.z, inv, b4.z);
  o.w = fmaf(acc.w, inv, b4.w);
  ((float4*)out)[((size_t)t * NN + n) * 8 + p] = o;
}

// ---------------- LSTM, all t in one kernel: weights in VGPRs, h/c in LDS ------------------

__global__ __launch_bounds__(256) void k_lstm_all(const float* __restrict__ agg2o,
    const float* __restrict__ w_ih, const float* __restrict__ w_hh,
    const float* __restrict__ b_ih, const float* __restrict__ b_hh,
    float* __restrict__ out) {
  __shared__ float xs[16 * 32], hs[16 * 32], cs[16 * 32], pre[16 * 128];
  int tid = threadIdx.x;
  int slot = tid >> 7;
  int r = tid & 127;
  float4 wi[8], wh[8];
  const float4* wi4 = (const float4*)(w_ih + r * 32);
  const float4* wh4 = (const float4*)(w_hh + r * 32);
  #pragma unroll
  for (int q = 0; q < 8; ++q) { wi[q] = wi4[q]; wh[q] = wh4[q]; }
  float bias = b_ih[r] + b_hh[r];
  int base = blockIdx.x * 16;
  for (int i = tid; i < 512; i += 256) { hs[i] = 0.f; cs[i] = 0.f; }
  for (int t = 0; t < TT; ++t) {
    for (int i = tid; i < 512; i += 256) xs[i] = agg2o[(size_t)t * NN * 32 + base * 32 + i];
    __syncthreads();
    #pragma unroll
    for (int g = 0; g < 8; ++g) {
      int nl = slot * 8 + g;
      const float4* xv4 = (const float4*)(xs + nl * 32);
      const float4* hv4 = (const float4*)(hs + nl * 32);
      float acc = bias;
      #pragma unroll
      for (int q = 0; q < 8; ++q) {
        float4 a = xv4[q], b = hv4[q];
        acc = fmaf(a.x, wi[q].x, acc);
        acc = fmaf(a.y, wi[q].y, acc);
        acc = fmaf(a.z, wi[q].z, acc);
        acc = fmaf(a.w, wi[q].w, acc);
        acc = fmaf(b.x, wh[q].x, acc);
        acc = fmaf(b.y, wh[q].y, acc);
        acc = fmaf(b.z, wh[q].z, acc);
        acc = fmaf(b.w, wh[q].w, acc);
      }
      pre[nl * 128 + r] = acc;
    }
    __syncthreads();
    for (int i = tid; i < 512; i += 256) {
      int nl = i >> 5, k = i & 31;
      float ai = pre[nl * 128 + k];
      float af = pre[nl * 128 + 32 + k];
      float ag = pre[nl * 128 + 64 + k];
      float ao = pre[nl * 128 + 96 + k];
      float ii = 1.f / (1.f + __expf(-ai));
      float ff = 1.f / (1.f + __expf(-af));
      float gg = tanhf(ag);
      float oo = 1.f / (1.f + __expf(-ao));
      float cn = fmaf(ff, cs[i], ii * gg);
      float hn = oo * tanhf(cn);
      cs[i] = cn; hs[i] = hn;
      out[(size_t)t * NN * 32 + base * 32 + i] = hn;
    }
  }
}

// ---------------- softmax over nodes, coalesced two-pass ----------------

__global__ __launch_bounds__(256) void k_sm_sum(const float* __restrict__ out, float* __restrict__ sums) {
  int t = blockIdx.y;
  const float4* b4 = (const float4*)(out + ((size_t)t * NN + blockIdx.x * 800) * CD);
  int tid = threadIdx.x;
  float4 s4 = make_float4(0.f, 0.f, 0.f, 0.f);
  for (int i = tid; i < 6400; i += 256) {
    float4 v = b4[i];
    s4.x += __expf(v.x); s4.y += __expf(v.y);
    s4.z += __expf(v.z); s4.w += __expf(v.w);
  }
  __shared__ float4 red[256];
  red[tid] = s4;
  __syncthreads();
  for (int off = 128; off >= 8; off >>= 1) {
    if (tid < off) {
      float4 o = red[tid + off];
      red[tid].x += o.x; red[tid].y += o.y; red[tid].z += o.z; red[tid].w += o.w;
    }
    __syncthreads();
  }
  if (tid < 8) {
    float4 v = red[tid];
    int c0 = tid * 4;
    atomicAdd(&sums[t * CD + c0 + 0], v.x);
    atomicAdd(&sums[t * CD + c0 + 1], v.y);
    atomicAdd(&sums[t * CD + c0 + 2], v.z);
    atomicAdd(&sums[t * CD + c0 + 3], v.w);
  }
}

__global__ __launch_bounds__(256) void k_sm_scale(float* __restrict__ out, const float* __restrict__ sums) {
  int t = blockIdx.y;
  __shared__ float inv[CD];
  int tid = threadIdx.x;
  if (tid < CD) inv[tid] = 1.f / sums[t * CD + tid];
  __syncthreads();
  float4* b4 = (float4*)(out + ((size_t)t * NN + blockIdx.x * 800) * CD);
  for (int i = tid; i < 6400; i += 256) {
    float4 v = b4[i];
    int c0 = (4 * i) & 31;
    v.x = __expf(v.x) * inv[c0];
    v.y = __expf(v.y) * inv[c0 + 1];
    v.z = __expf(v.z) * inv[c0 + 2];
    v.w = __expf(v.w) * inv[c0 + 3];
    b4[i] = v;
  }
}

// ---------------- launch ----------------

extern "C" void kernel_launch(void* const* d_in, const int* in_sizes, int n_in,
                              void* d_out, int out_size, void* d_ws, size_t ws_size,
                              hipStream_t stream) {
  const float* x   = (const float*)d_in[0];
  const float* W1  = (const float*)d_in[1];
  const float* as1 = (const float*)d_in[2];
  const float* ad1 = (const float*)d_in[3];
  const float* b1  = (const float*)d_in[4];
  const float* W2  = (const float*)d_in[5];
  const float* as2 = (const float*)d_in[6];
  const float* ad2 = (const float*)d_in[7];
  const float* b2  = (const float*)d_in[8];
  const float* wih = (const float*)d_in[9];
  const float* whh = (const float*)d_in[10];
  const float* bih = (const float*)d_in[11];
  const float* bhh = (const float*)d_in[12];
  const int*   ei  = (const int*)d_in[13];
  const int* srcp = ei;
  const int* dstp = ei + NE;
  float* out = (float*)d_out;

  float* ws = (float*)d_ws;
  float* h2    = ws;  ws += (size_t)TT * NN * CD;
  float* al2s  = ws;  ws += (size_t)TT * NN;
  float* al2d  = ws;  ws += (size_t)TT * NN;
  float* al1s  = ws;  ws += (size_t)TT * NN * 8;
  float* al1d  = ws;  ws += (size_t)TT * NN * 8;
  float* agg2o = ws;  ws += (size_t)TT * NN * CD;
  float* sums  = ws;  ws += TT * CD;
  float* wsrc  = ws;  ws += 256;
  float* wdst  = ws;  ws += 256;
  float* W1T   = ws;  ws += D1 * 32;
  float* W2T   = ws;  ws += 32 * D1;
  int* rowptr = (int*)ws;
  int* fill   = rowptr + NN + 1;
  int* csr    = fill + NN;
  int* deg    = csr + NE;

  hipMemsetAsync(sums, 0, TT * CD * sizeof(float), stream);
  hipMemsetAsync(deg, 0, NN * sizeof(int), stream);

  k_deg<<<(NE + 255) / 256, 256, 0, stream>>>(dstp, deg);
  k_scan<<<1, 1024, 0, stream>>>(deg, rowptr, fill);
  k_fill<<<(NE + 255) / 256, 256, 0, stream>>>(srcp, dstp, fill, csr);
  k_prew<<<1, 256, 0, stream>>>(W1, as1, ad1, W2, wsrc, wdst, W1T, W2T);

  k_logits8<<<(NN / 32) * TT, 256, 0, stream>>>(x, wsrc, wdst, al1s, al1d);
  k_gat1<<<NN / 4, 256, 0, stream>>>(x, al1s, al1d, rowptr, csr,
                                     W1T, b1, W2T, as2, ad2, h2, al2s, al2d);
  k_agg2<<<NN / 4, 256, 0, stream>>>(h2, al2s, al2d, rowptr, csr, b2, agg2o);
  k_lstm_all<<<NN / 16, 256, 0, stream>>>(agg2o, wih, whh, bih, bhh, out);

  k_sm_sum<<<dim3(25, TT), 256, 0, stream>>>(out, sums);
  k_sm_scale<<<dim3(25, TT), 256, 0, stream>>>(out, sums);
}

// Round 9
// 596.047 us; speedup vs baseline: 2.5868x; 2.5868x over previous
//
#include <hip/hip_runtime.h>
#include <math.h>

#define NN 20000   // nodes
#define NE 320000  // edges (without self-loops)
#define TT 8       // timesteps
#define D1 256     // H*F layer-1 width
#define CD 32      // layer-2 width == LSTM hidden

// ---------------- CSR build (once per launch; edges identical across t) ----------------

__global__ __launch_bounds__(256) void k_deg(const int* __restrict__ dst, int* __restrict__ deg) {
  int e = blockIdx.x * 256 + threadIdx.x;
  if (e < NE) atomicAdd(&deg[dst[e]], 1);
}

__global__ __launch_bounds__(1024) void k_scan(const int* __restrict__ deg,
                                               int* __restrict__ rowptr, int* __restrict__ fill) {
  __shared__ int sd[1024];
  __shared__ int carry_s;
  int tid = threadIdx.x;
  if (tid == 0) { carry_s = 0; rowptr[0] = 0; }
  __syncthreads();
  for (int base = 0; base < NN; base += 1024) {
    int i = base + tid;
    int v = (i < NN) ? deg[i] : 0;
    sd[tid] = v;
    __syncthreads();
    for (int off = 1; off < 1024; off <<= 1) {
      int t = (tid >= off) ? sd[tid - off] : 0;
      __syncthreads();
      sd[tid] += t;
      __syncthreads();
    }
    int incl = sd[tid];
    int carry = carry_s;
    if (i < NN) { rowptr[i + 1] = carry + incl; fill[i] = carry + incl - v; }
    __syncthreads();
    if (tid == 1023) carry_s = carry + sd[1023];
    __syncthreads();
  }
}

__global__ __launch_bounds__(256) void k_fill(const int* __restrict__ src, const int* __restrict__ dst,
                                              int* __restrict__ fill, int* __restrict__ csr) {
  int e = blockIdx.x * 256 + threadIdx.x;
  if (e < NE) {
    int pos = atomicAdd(&fill[dst[e]], 1);
    csr[pos] = src[e];
  }
}

// ---------------- one-time: folded attention vectors + weight transposes --------------------

__global__ __launch_bounds__(256) void k_prew(const float* __restrict__ W1,
    const float* __restrict__ as1, const float* __restrict__ ad1,
    const float* __restrict__ W2,
    float* __restrict__ wsrc, float* __restrict__ wdst,
    float* __restrict__ W1T, float* __restrict__ W2T) {
  int tid = threadIdx.x;
  int k = tid >> 3, h = tid & 7;
  float s = 0.f, d = 0.f;
  #pragma unroll
  for (int f = 0; f < 32; ++f) {
    float wv = W1[k * D1 + h * 32 + f];
    s = fmaf(wv, as1[h * 32 + f], s);
    d = fmaf(wv, ad1[h * 32 + f], d);
  }
  wsrc[k * 8 + h] = s;
  wdst[k * 8 + h] = d;
  for (int i = tid; i < D1 * 32; i += 256) {
    int j = i >> 5, kk = i & 31;
    W1T[i] = W1[kk * D1 + j];          // W1T[j*32+kk]
  }
  for (int i = tid; i < 32 * D1; i += 256) {
    int f = i >> 8, kk = i & 255;
    W2T[i] = W2[kk * CD + f];          // W2T[f*256+kk]
  }
}

// ---------------- logits for all t: als/ald = x @ w~ ; t = blockIdx.x & 7 -------------------

__global__ __launch_bounds__(256) void k_logits8(const float* __restrict__ x,
    const float* __restrict__ wsrc, const float* __restrict__ wdst,
    float* __restrict__ als, float* __restrict__ ald) {
  __shared__ float xs[32 * 33];
  __shared__ float wsr[256], wdr[256];
  int tid = threadIdx.x;
  int t = blockIdx.x & 7;
  int n0 = (blockIdx.x >> 3) * 32;
  const float* xt = x + (size_t)t * NN * 32;
  int nl = tid >> 3, h = tid & 7;
  for (int i = tid; i < 1024; i += 256) {
    int g = i >> 5, k = i & 31;
    xs[g * 33 + k] = xt[n0 * 32 + i];
  }
  wsr[tid] = wsrc[tid];
  wdr[tid] = wdst[tid];
  __syncthreads();
  const float* xr = xs + nl * 33;
  float as = 0.f, ad = 0.f;
  #pragma unroll
  for (int k = 0; k < 32; ++k) {
    float xv = xr[k];
    as = fmaf(xv, wsr[k * 8 + h], as);
    ad = fmaf(xv, wdr[k * 8 + h], ad);
  }
  als[(size_t)t * NN * 8 + n0 * 8 + tid] = as;
  ald[(size_t)t * NN * 8 + n0 * 8 + tid] = ad;
}

// ---------------- layer-1 gather, ALL t in one wave: wave=node, lane=(t,h), 2-edge unroll ---
// (256,2): VGPR cap 128; compiler chooses 48 regardless (measured r4/r5) -- keep the headroom.

__global__ __launch_bounds__(256, 2) void k_gat1(const float* __restrict__ x,
    const float* __restrict__ als, const float* __restrict__ ald,
    const int* __restrict__ rowptr, const int* __restrict__ csr,
    float* __restrict__ aggx, float* __restrict__ den1) {
  int tid = threadIdx.x;
  int wv = tid >> 6, lane = tid & 63;
  int t = lane >> 3, h = lane & 7;
  int n = blockIdx.x * 4 + wv;
  const float* alst = als + (size_t)t * NN * 8 + h;           // + s*8 per edge
  float adv = ald[(size_t)t * NN * 8 + (size_t)n * 8 + h];
  const float4* x4t = (const float4*)(x + (size_t)t * NN * 32);
  float4 acc[8];
  #pragma unroll
  for (int q = 0; q < 8; ++q) acc[q] = make_float4(0.f, 0.f, 0.f, 0.f);
  float den = 0.f;
  int beg = rowptr[n], end = rowptr[n + 1];
  // virtual list [beg, end]: edges then self-loop at position `end`
  int v = beg;
  for (; v + 1 <= end; v += 2) {
    int s0 = csr[v];                              // v < end guaranteed here
    int s1 = (v + 1 < end) ? csr[v + 1] : n;
    float a0 = alst[(size_t)s0 * 8] + adv;
    float a1 = alst[(size_t)s1 * 8] + adv;
    const float4* xr0 = x4t + (size_t)s0 * 8;
    const float4* xr1 = x4t + (size_t)s1 * 8;
    a0 = fmaxf(a0, 0.2f * a0);
    a1 = fmaxf(a1, 0.2f * a1);
    float e0 = __expf(a0), e1 = __expf(a1);
    float4 u0 = xr0[0], u1 = xr0[1], u2 = xr0[2], u3 = xr0[3];
    float4 u4 = xr0[4], u5 = xr0[5], u6 = xr0[6], u7 = xr0[7];
    float4 w0 = xr1[0], w1 = xr1[1], w2 = xr1[2], w3 = xr1[3];
    float4 w4 = xr1[4], w5 = xr1[5], w6 = xr1[6], w7 = xr1[7];
    acc[0].x = fmaf(e1, w0.x, fmaf(e0, u0.x, acc[0].x));
    acc[0].y = fmaf(e1, w0.y, fmaf(e0, u0.y, acc[0].y));
    acc[0].z = fmaf(e1, w0.z, fmaf(e0, u0.z, acc[0].z));
    acc[0].w = fmaf(e1, w0.w, fmaf(e0, u0.w, acc[0].w));
    acc[1].x = fmaf(e1, w1.x, fmaf(e0, u1.x, acc[1].x));
    acc[1].y = fmaf(e1, w1.y, fmaf(e0, u1.y, acc[1].y));
    acc[1].z = fmaf(e1, w1.z, fmaf(e0, u1.z, acc[1].z));
    acc[1].w = fmaf(e1, w1.w, fmaf(e0, u1.w, acc[1].w));
    acc[2].x = fmaf(e1, w2.x, fmaf(e0, u2.x, acc[2].x));
    acc[2].y = fmaf(e1, w2.y, fmaf(e0, u2.y, acc[2].y));
    acc[2].z = fmaf(e1, w2.z, fmaf(e0, u2.z, acc[2].z));
    acc[2].w = fmaf(e1, w2.w, fmaf(e0, u2.w, acc[2].w));
    acc[3].x = fmaf(e1, w3.x, fmaf(e0, u3.x, acc[3].x));
    acc[3].y = fmaf(e1, w3.y, fmaf(e0, u3.y, acc[3].y));
    acc[3].z = fmaf(e1, w3.z, fmaf(e0, u3.z, acc[3].z));
    acc[3].w = fmaf(e1, w3.w, fmaf(e0, u3.w, acc[3].w));
    acc[4].x = fmaf(e1, w4.x, fmaf(e0, u4.x, acc[4].x));
    acc[4].y = fmaf(e1, w4.y, fmaf(e0, u4.y, acc[4].y));
    acc[4].z = fmaf(e1, w4.z, fmaf(e0, u4.z, acc[4].z));
    acc[4].w = fmaf(e1, w4.w, fmaf(e0, u4.w, acc[4].w));
    acc[5].x = fmaf(e1, w5.x, fmaf(e0, u5.x, acc[5].x));
    acc[5].y = fmaf(e1, w5.y, fmaf(e0, u5.y, acc[5].y));
    acc[5].z = fmaf(e1, w5.z, fmaf(e0, u5.z, acc[5].z));
    acc[5].w = fmaf(e1, w5.w, fmaf(e0, u5.w, acc[5].w));
    acc[6].x = fmaf(e1, w6.x, fmaf(e0, u6.x, acc[6].x));
    acc[6].y = fmaf(e1, w6.y, fmaf(e0, u6.y, acc[6].y));
    acc[6].z = fmaf(e1, w6.z, fmaf(e0, u6.z, acc[6].z));
    acc[6].w = fmaf(e1, w6.w, fmaf(e0, u6.w, acc[6].w));
    acc[7].x = fmaf(e1, w7.x, fmaf(e0, u7.x, acc[7].x));
    acc[7].y = fmaf(e1, w7.y, fmaf(e0, u7.y, acc[7].y));
    acc[7].z = fmaf(e1, w7.z, fmaf(e0, u7.z, acc[7].z));
    acc[7].w = fmaf(e1, w7.w, fmaf(e0, u7.w, acc[7].w));
    den += e0 + e1;
  }
  if (v <= end) {                                 // 1 leftover (edge or self-loop)
    int s = (v < end) ? csr[v] : n;
    float a = alst[(size_t)s * 8] + adv;
    a = fmaxf(a, 0.2f * a);
    float e = __expf(a);
    const float4* xr = x4t + (size_t)s * 8;
    #pragma unroll
    for (int q = 0; q < 8; ++q) {
      float4 xv = xr[q];
      acc[q].x = fmaf(e, xv.x, acc[q].x);
      acc[q].y = fmaf(e, xv.y, acc[q].y);
      acc[q].z = fmaf(e, xv.z, acc[q].z);
      acc[q].w = fmaf(e, xv.w, acc[q].w);
    }
    den += e;
  }
  float4* ao = (float4*)(aggx + ((size_t)t * NN + n) * 256 + h * 32);
  #pragma unroll
  for (int q = 0; q < 8; ++q) ao[q] = acc[q];
  den1[((size_t)t * NN + n) * 8 + h] = den;
}

// ---------------- dense epilogue: 16-node tiles, 8 tiles/block, weights resident -----------
// launch_bounds(256,1): VGPR unconstrained (~112 used) so the 32 float4 of weights truly
// live in registers (round-8 proved per-thread weight STREAMING is 8x worse: 64KB/wave
// working set thrashes the 32KB L1 -> 1250us). PTILES=8: each block owns one 16-node group
// across ALL 8 t (tile=blk*8+it -> t=it, n0=blk*16) -- weight load amortized 8x, aggx/den1
// locality per block. Grid 1250.

#define PTILES 8

__global__ __launch_bounds__(256, 1) void k_post(const float* __restrict__ aggx,
    const float* __restrict__ den1, const float* __restrict__ W1T, const float* __restrict__ b1,
    const float* __restrict__ W2T, const float* __restrict__ as2, const float* __restrict__ ad2,
    float* __restrict__ h2, float* __restrict__ al2s, float* __restrict__ al2d) {
  __shared__ float aggs[16 * 256];   // phase-2 input; aliased as part[8][16][32] in phase 3
  __shared__ float rels[16 * 256];
  __shared__ float dens[16 * 8];     // INVERSE denominators
  float* part = aggs;                // 8*16*32 == 16*256 floats exactly
  int tid = threadIdx.x;

  int u = tid & 127, grp = tid >> 7;
  int j0 = 2 * u;
  int hj = j0 >> 5;
  // one-time per block: weights + biases into registers (amortized over PTILES tiles)
  float4 w1a[8], w1b[8];
  const float4* w1p = (const float4*)(W1T + j0 * 32);
  #pragma unroll
  for (int q8 = 0; q8 < 8; ++q8) { w1a[q8] = w1p[q8]; w1b[q8] = w1p[q8 + 8]; }
  float bj0 = b1[j0], bj1 = b1[j0 + 1];
  int q = u >> 4, fp = u & 15, f0 = 2 * fp;
  float4 w2a[8], w2b[8];
  const float4* w2pa = (const float4*)(W2T + f0 * 256 + q * 32);
  const float4* w2pb = (const float4*)(W2T + (f0 + 1) * 256 + q * 32);
  #pragma unroll
  for (int q8 = 0; q8 < 8; ++q8) { w2a[q8] = w2pa[q8]; w2b[q8] = w2pb[q8]; }
  float as2f = as2[tid & 31], ad2f = ad2[tid & 31];

  for (int it = 0; it < PTILES; ++it) {
    int tile = blockIdx.x * PTILES + it;
    int t = tile & 7;
    int n0 = (tile >> 3) * 16;

    if (it > 0) __syncthreads();     // part/dens reads of prev tile done before overwrite

    const float4* ag4 = (const float4*)(aggx + ((size_t)t * NN + n0) * 256);
    float4* as4 = (float4*)aggs;
    #pragma unroll
    for (int k = 0; k < 4; ++k) as4[tid + k * 256] = ag4[tid + k * 256];
    if (tid < 128) dens[tid] = 1.f / den1[((size_t)t * NN + n0) * 8 + tid];
    __syncthreads();

    // phase 2: rows grp*8..+7, columns j0, j0+1 (aggs reads shared by both columns)
    #pragma unroll
    for (int g = 0; g < 8; ++g) {
      int row = grp * 8 + g;
      const float4* ar4 = (const float4*)(aggs + row * 256 + hj * 32);
      float a0 = 0.f, a1 = 0.f;
      #pragma unroll
      for (int k4 = 0; k4 < 8; ++k4) {
        float4 av = ar4[k4];
        a0 = fmaf(av.x, w1a[k4].x, fmaf(av.y, w1a[k4].y,
             fmaf(av.z, w1a[k4].z, fmaf(av.w, w1a[k4].w, a0))));
        a1 = fmaf(av.x, w1b[k4].x, fmaf(av.y, w1b[k4].y,
             fmaf(av.z, w1b[k4].z, fmaf(av.w, w1b[k4].w, a1))));
      }
      float invd = dens[row * 8 + hj];
      float2 r;
      r.x = fmaxf(fmaf(a0, invd, bj0), 0.f);
      r.y = fmaxf(fmaf(a1, invd, bj1), 0.f);
      *(float2*)(rels + row * 256 + j0) = r;
    }
    __syncthreads();   // rels ready; aggs dead -> reuse as part

    // phase 3: q-split over K (8 chunks of 32), columns f0, f0+1
    #pragma unroll
    for (int g = 0; g < 8; ++g) {
      int row = grp * 8 + g;
      const float4* r4 = (const float4*)(rels + row * 256 + q * 32);
      float a0 = 0.f, a1 = 0.f;
      #pragma unroll
      for (int jj = 0; jj < 8; ++jj) {
        float4 a4 = r4[jj];
        a0 = fmaf(a4.x, w2a[jj].x, fmaf(a4.y, w2a[jj].y,
             fmaf(a4.z, w2a[jj].z, fmaf(a4.w, w2a[jj].w, a0))));
        a1 = fmaf(a4.x, w2b[jj].x, fmaf(a4.y, w2b[jj].y,
             fmaf(a4.z, w2b[jj].z, fmaf(a4.w, w2b[jj].w, a1))));
      }
      float2 pr; pr.x = a0; pr.y = a1;
      *(float2*)(part + q * 512 + row * 32 + f0) = pr;
    }
    __syncthreads();

    // reduce over q + h2 write + layer-2 logits
    #pragma unroll
    for (int rep = 0; rep < 2; ++rep) {
      int row = (tid >> 5) + rep * 8;
      int ff = tid & 31;
      float v = 0.f;
      #pragma unroll
      for (int qq = 0; qq < 8; ++qq) v += part[qq * 512 + row * 32 + ff];
      int nn = n0 + row;
      h2[((size_t)t * NN + nn) * CD + ff] = v;
      float vs = v * as2f, vd = v * ad2f;
      #pragma unroll
      for (int m = 1; m < 32; m <<= 1) {
        vs += __shfl_xor(vs, m, 64);
        vd += __shfl_xor(vd, m, 64);
      }
      if (ff == 0) {
        al2s[(size_t)t * NN + nn] = vs;
        al2d[(size_t)t * NN + nn] = vd;
      }
    }
  }
}

// ---------------- layer-2 aggregation, ALL t in one wave: lane=(t, f-quad), 2-edge unroll ---

__global__ __launch_bounds__(256, 4) void k_agg2(const float* __restrict__ h2,
    const float* __restrict__ al2s, const float* __restrict__ al2d,
    const int* __restrict__ rowptr, const int* __restrict__ csr,
    const float* __restrict__ b2, float* __restrict__ out) {
  int tid = threadIdx.x;
  int wv = tid >> 6, lane = tid & 63;
  int t = lane >> 3, p = lane & 7;
  int n = blockIdx.x * 4 + wv;
  const float* alst = al2s + (size_t)t * NN;
  float adv = al2d[(size_t)t * NN + n];
  const float4* h24 = (const float4*)h2 + (size_t)t * NN * 8 + p;
  float4 b4 = ((const float4*)b2)[p];
  float4 acc = make_float4(0.f, 0.f, 0.f, 0.f);
  float den = 0.f;
  int beg = rowptr[n], end = rowptr[n + 1];
  int v = beg;
  for (; v + 1 <= end; v += 2) {
    int s0 = csr[v];
    int s1 = (v + 1 < end) ? csr[v + 1] : n;
    float a0 = alst[s0] + adv;
    float a1 = alst[s1] + adv;
    float4 u = h24[(size_t)s0 * 8];
    float4 w = h24[(size_t)s1 * 8];
    a0 = fmaxf(a0, 0.2f * a0);
    a1 = fmaxf(a1, 0.2f * a1);
    float e0 = __expf(a0), e1 = __expf(a1);
    acc.x = fmaf(e1, w.x, fmaf(e0, u.x, acc.x));
    acc.y = fmaf(e1, w.y, fmaf(e0, u.y, acc.y));
    acc.z = fmaf(e1, w.z, fmaf(e0, u.z, acc.z));
    acc.w = fmaf(e1, w.w, fmaf(e0, u.w, acc.w));
    den += e0 + e1;
  }
  if (v <= end) {
    int s = (v < end) ? csr[v] : n;
    float a = alst[s] + adv;
    a = fmaxf(a, 0.2f * a);
    float e = __expf(a);
    float4 u = h24[(size_t)s * 8];
    acc.x = fmaf(e, u.x, acc.x);
    acc.y = fmaf(e, u.y, acc.y);
    acc.z = fmaf(e, u.z, acc.z);
    acc.w = fmaf(e, u.w, acc.w);
    den += e;
  }
  float inv = 1.f / den;
  float4 o;
  o.x = fmaf(acc.x, inv, b4.x);
  o.y = fmaf(acc.y, inv, b4.y);
  o.z = fmaf(acc.z, inv, b4.z);
  o.w = fmaf(acc.w, inv, b4.w);
  ((float4*)out)[((size_t)t * NN + n) * 8 + p] = o;
}

// ---------------- LSTM, all t in one kernel: weights in VGPRs, h/c in LDS ------------------

__global__ __launch_bounds__(256) void k_lstm_all(const float* __restrict__ agg2o,
    const float* __restrict__ w_ih, const float* __restrict__ w_hh,
    const float* __restrict__ b_ih, const float* __restrict__ b_hh,
    float* __restrict__ out) {
  __shared__ float xs[16 * 32], hs[16 * 32], cs[16 * 32], pre[16 * 128];
  int tid = threadIdx.x;
  int slot = tid >> 7;
  int r = tid & 127;
  float4 wi[8], wh[8];
  const float4* wi4 = (const float4*)(w_ih + r * 32);
  const float4* wh4 = (const float4*)(w_hh + r * 32);
  #pragma unroll
  for (int q = 0; q < 8; ++q) { wi[q] = wi4[q]; wh[q] = wh4[q]; }
  float bias = b_ih[r] + b_hh[r];
  int base = blockIdx.x * 16;
  for (int i = tid; i < 512; i += 256) { hs[i] = 0.f; cs[i] = 0.f; }
  for (int t = 0; t < TT; ++t) {
    for (int i = tid; i < 512; i += 256) xs[i] = agg2o[(size_t)t * NN * 32 + base * 32 + i];
    __syncthreads();
    #pragma unroll
    for (int g = 0; g < 8; ++g) {
      int nl = slot * 8 + g;
      const float4* xv4 = (const float4*)(xs + nl * 32);
      const float4* hv4 = (const float4*)(hs + nl * 32);
      float acc = bias;
      #pragma unroll
      for (int q = 0; q < 8; ++q) {
        float4 a = xv4[q], b = hv4[q];
        acc = fmaf(a.x, wi[q].x, acc);
        acc = fmaf(a.y, wi[q].y, acc);
        acc = fmaf(a.z, wi[q].z, acc);
        acc = fmaf(a.w, wi[q].w, acc);
        acc = fmaf(b.x, wh[q].x, acc);
        acc = fmaf(b.y, wh[q].y, acc);
        acc = fmaf(b.z, wh[q].z, acc);
        acc = fmaf(b.w, wh[q].w, acc);
      }
      pre[nl * 128 + r] = acc;
    }
    __syncthreads();
    for (int i = tid; i < 512; i += 256) {
      int nl = i >> 5, k = i & 31;
      float ai = pre[nl * 128 + k];
      float af = pre[nl * 128 + 32 + k];
      float ag = pre[nl * 128 + 64 + k];
      float ao = pre[nl * 128 + 96 + k];
      float ii = 1.f / (1.f + __expf(-ai));
      float ff = 1.f / (1.f + __expf(-af));
      float gg = tanhf(ag);
      float oo = 1.f / (1.f + __expf(-ao));
      float cn = fmaf(ff, cs[i], ii * gg);
      float hn = oo * tanhf(cn);
      cs[i] = cn; hs[i] = hn;
      out[(size_t)t * NN * 32 + base * 32 + i] = hn;
    }
  }
}

// ---------------- softmax over nodes, coalesced two-pass ----------------

__global__ __launch_bounds__(256) void k_sm_sum(const float* __restrict__ out, float* __restrict__ sums) {
  int t = blockIdx.y;
  const float4* b4 = (const float4*)(out + ((size_t)t * NN + blockIdx.x * 800) * CD);
  int tid = threadIdx.x;
  float4 s4 = make_float4(0.f, 0.f, 0.f, 0.f);
  for (int i = tid; i < 6400; i += 256) {
    float4 v = b4[i];
    s4.x += __expf(v.x); s4.y += __expf(v.y);
    s4.z += __expf(v.z); s4.w += __expf(v.w);
  }
  __shared__ float4 red[256];
  red[tid] = s4;
  __syncthreads();
  for (int off = 128; off >= 8; off >>= 1) {
    if (tid < off) {
      float4 o = red[tid + off];
      red[tid].x += o.x; red[tid].y += o.y; red[tid].z += o.z; red[tid].w += o.w;
    }
    __syncthreads();
  }
  if (tid < 8) {
    float4 v = red[tid];
    int c0 = tid * 4;
    atomicAdd(&sums[t * CD + c0 + 0], v.x);
    atomicAdd(&sums[t * CD + c0 + 1], v.y);
    atomicAdd(&sums[t * CD + c0 + 2], v.z);
    atomicAdd(&sums[t * CD + c0 + 3], v.w);
  }
}

__global__ __launch_bounds__(256) void k_sm_scale(float* __restrict__ out, const float* __restrict__ sums) {
  int t = blockIdx.y;
  __shared__ float inv[CD];
  int tid = threadIdx.x;
  if (tid < CD) inv[tid] = 1.f / sums[t * CD + tid];
  __syncthreads();
  float4* b4 = (float4*)(out + ((size_t)t * NN + blockIdx.x * 800) * CD);
  for (int i = tid; i < 6400; i += 256) {
    float4 v = b4[i];
    int c0 = (4 * i) & 31;
    v.x = __expf(v.x) * inv[c0];
    v.y = __expf(v.y) * inv[c0 + 1];
    v.z = __expf(v.z) * inv[c0 + 2];
    v.w = __expf(v.w) * inv[c0 + 3];
    b4[i] = v;
  }
}

// ---------------- launch ----------------

extern "C" void kernel_launch(void* const* d_in, const int* in_sizes, int n_in,
                              void* d_out, int out_size, void* d_ws, size_t ws_size,
                              hipStream_t stream) {
  const float* x   = (const float*)d_in[0];
  const float* W1  = (const float*)d_in[1];
  const float* as1 = (const float*)d_in[2];
  const float* ad1 = (const float*)d_in[3];
  const float* b1  = (const float*)d_in[4];
  const float* W2  = (const float*)d_in[5];
  const float* as2 = (const float*)d_in[6];
  const float* ad2 = (const float*)d_in[7];
  const float* b2  = (const float*)d_in[8];
  const float* wih = (const float*)d_in[9];
  const float* whh = (const float*)d_in[10];
  const float* bih = (const float*)d_in[11];
  const float* bhh = (const float*)d_in[12];
  const int*   ei  = (const int*)d_in[13];
  const int* srcp = ei;
  const int* dstp = ei + NE;
  float* out = (float*)d_out;

  float* ws = (float*)d_ws;
  float* aggx  = ws;  ws += (size_t)TT * NN * 256;   // 164 MB
  float* den1  = ws;  ws += (size_t)TT * NN * 8;
  float* al1s  = ws;  ws += (size_t)TT * NN * 8;
  float* al1d  = ws;  ws += (size_t)TT * NN * 8;
  float* h2    = ws;  ws += (size_t)TT * NN * CD;
  float* al2s  = ws;  ws += (size_t)TT * NN;
  float* al2d  = ws;  ws += (size_t)TT * NN;
  float* agg2o = ws;  ws += (size_t)TT * NN * CD;
  float* sums  = ws;  ws += TT * CD;
  float* wsrc  = ws;  ws += 256;
  float* wdst  = ws;  ws += 256;
  float* W1T   = ws;  ws += D1 * 32;
  float* W2T   = ws;  ws += 32 * D1;
  int* rowptr = (int*)ws;
  int* fill   = rowptr + NN + 1;
  int* csr    = fill + NN;
  int* deg    = csr + NE;

  hipMemsetAsync(sums, 0, TT * CD * sizeof(float), stream);
  hipMemsetAsync(deg, 0, NN * sizeof(int), stream);

  k_deg<<<(NE + 255) / 256, 256, 0, stream>>>(dstp, deg);
  k_scan<<<1, 1024, 0, stream>>>(deg, rowptr, fill);
  k_fill<<<(NE + 255) / 256, 256, 0, stream>>>(srcp, dstp, fill, csr);
  k_prew<<<1, 256, 0, stream>>>(W1, as1, ad1, W2, wsrc, wdst, W1T, W2T);

  k_logits8<<<(NN / 32) * TT, 256, 0, stream>>>(x, wsrc, wdst, al1s, al1d);
  k_gat1<<<NN / 4, 256, 0, stream>>>(x, al1s, al1d, rowptr, csr, aggx, den1);
  k_post<<<(NN / 16) * TT / PTILES, 256, 0, stream>>>(aggx, den1, W1T, b1, W2T, as2, ad2,
                                                      h2, al2s, al2d);
  k_agg2<<<NN / 4, 256, 0, stream>>>(h2, al2s, al2d, rowptr, csr, b2, agg2o);
  k_lstm_all<<<NN / 16, 256, 0, stream>>>(agg2o, wih, whh, bih, bhh, out);

  k_sm_sum<<<dim3(25, TT), 256, 0, stream>>>(out, sums);
  k_sm_scale<<<dim3(25, TT), 256, 0, stream>>>(out, sums);
}

// Round 10
// 587.326 us; speedup vs baseline: 2.6252x; 1.0148x over previous
//
#include <hip/hip_runtime.h>
#include <math.h>

#define NN 20000   // nodes
#define NE 320000  // edges (without self-loops)
#define TT 8       // timesteps
#define D1 256     // H*F layer-1 width
#define CD 32      // layer-2 width == LSTM hidden

// ---------------- CSR build (once per launch; edges identical across t) ----------------

__global__ __launch_bounds__(256) void k_deg(const int* __restrict__ dst, int* __restrict__ deg) {
  int e = blockIdx.x * 256 + threadIdx.x;
  if (e < NE) atomicAdd(&deg[dst[e]], 1);
}

__global__ __launch_bounds__(1024) void k_scan(const int* __restrict__ deg,
                                               int* __restrict__ rowptr, int* __restrict__ fill) {
  __shared__ int sd[1024];
  __shared__ int carry_s;
  int tid = threadIdx.x;
  if (tid == 0) { carry_s = 0; rowptr[0] = 0; }
  __syncthreads();
  for (int base = 0; base < NN; base += 1024) {
    int i = base + tid;
    int v = (i < NN) ? deg[i] : 0;
    sd[tid] = v;
    __syncthreads();
    for (int off = 1; off < 1024; off <<= 1) {
      int t = (tid >= off) ? sd[tid - off] : 0;
      __syncthreads();
      sd[tid] += t;
      __syncthreads();
    }
    int incl = sd[tid];
    int carry = carry_s;
    if (i < NN) { rowptr[i + 1] = carry + incl; fill[i] = carry + incl - v; }
    __syncthreads();
    if (tid == 1023) carry_s = carry + sd[1023];
    __syncthreads();
  }
}

__global__ __launch_bounds__(256) void k_fill(const int* __restrict__ src, const int* __restrict__ dst,
                                              int* __restrict__ fill, int* __restrict__ csr) {
  int e = blockIdx.x * 256 + threadIdx.x;
  if (e < NE) {
    int pos = atomicAdd(&fill[dst[e]], 1);
    csr[pos] = src[e];
  }
}

// ---------------- one-time: folded attention vectors + weight transposes --------------------

__global__ __launch_bounds__(256) void k_prew(const float* __restrict__ W1,
    const float* __restrict__ as1, const float* __restrict__ ad1,
    const float* __restrict__ W2,
    float* __restrict__ wsrc, float* __restrict__ wdst,
    float* __restrict__ W1T, float* __restrict__ W2T) {
  int tid = threadIdx.x;
  int k = tid >> 3, h = tid & 7;
  float s = 0.f, d = 0.f;
  #pragma unroll
  for (int f = 0; f < 32; ++f) {
    float wv = W1[k * D1 + h * 32 + f];
    s = fmaf(wv, as1[h * 32 + f], s);
    d = fmaf(wv, ad1[h * 32 + f], d);
  }
  wsrc[k * 8 + h] = s;
  wdst[k * 8 + h] = d;
  for (int i = tid; i < D1 * 32; i += 256) {
    int j = i >> 5, kk = i & 31;
    W1T[i] = W1[kk * D1 + j];          // W1T[j*32+kk]
  }
  for (int i = tid; i < 32 * D1; i += 256) {
    int f = i >> 8, kk = i & 255;
    W2T[i] = W2[kk * CD + f];          // W2T[f*256+kk]
  }
}

// ---------------- logits for all t: als/ald = x @ w~ ; t = blockIdx.x & 7 -------------------

__global__ __launch_bounds__(256) void k_logits8(const float* __restrict__ x,
    const float* __restrict__ wsrc, const float* __restrict__ wdst,
    float* __restrict__ als, float* __restrict__ ald) {
  __shared__ float xs[32 * 33];
  __shared__ float wsr[256], wdr[256];
  int tid = threadIdx.x;
  int t = blockIdx.x & 7;
  int n0 = (blockIdx.x >> 3) * 32;
  const float* xt = x + (size_t)t * NN * 32;
  int nl = tid >> 3, h = tid & 7;
  for (int i = tid; i < 1024; i += 256) {
    int g = i >> 5, k = i & 31;
    xs[g * 33 + k] = xt[n0 * 32 + i];
  }
  wsr[tid] = wsrc[tid];
  wdr[tid] = wdst[tid];
  __syncthreads();
  const float* xr = xs + nl * 33;
  float as = 0.f, ad = 0.f;
  #pragma unroll
  for (int k = 0; k < 32; ++k) {
    float xv = xr[k];
    as = fmaf(xv, wsr[k * 8 + h], as);
    ad = fmaf(xv, wdr[k * 8 + h], ad);
  }
  als[(size_t)t * NN * 8 + n0 * 8 + tid] = as;
  ald[(size_t)t * NN * 8 + n0 * 8 + tid] = ad;
}

// ---------------- layer-1 gather v2: wave = (node, t); lane = (h, f4) ----------------------
// r9 counters: FETCH 279 MB ~= the FULL 320K-edge x 8t x 128B gather volume -- the old
// lane=(t,h) layout made every wave touch all 8 t-slices of x (20.5 MB working set vs 4 MB
// per-XCD L2) so nothing cached. New: one wave owns one (n,t); all 8 heads scale the SAME
// x row, so per edge the wave loads ONE 128B x-segment + one 32B als-segment (f4-lanes
// broadcast). t = blockIdx&7 -> with round-robin block->XCD dispatch each XCD works one
// t-slice: x[t]+als/ald[t]+csr ~= 5 MB, mostly L2-resident. 8x more waves (160K) for TLP;
// acc = 1 float4 -> 4-edge unroll cheap. aggx/den1 layouts unchanged (k_post-compatible).
// aggx store: addr = base + lane*4 floats -> 1KB/wave fully coalesced.

__global__ __launch_bounds__(256, 2) void k_gat1(const float* __restrict__ x,
    const float* __restrict__ als, const float* __restrict__ ald,
    const int* __restrict__ rowptr, const int* __restrict__ csr,
    float* __restrict__ aggx, float* __restrict__ den1) {
  int tid = threadIdx.x;
  int wv = tid >> 6, lane = tid & 63;
  int h = lane >> 3, f4 = lane & 7;
  int t = blockIdx.x & 7;
  int n = (blockIdx.x >> 3) * 4 + wv;
  const float* alst = als + (size_t)t * NN * 8 + h;           // + s*8 per edge
  float adv = ald[(size_t)t * NN * 8 + (size_t)n * 8 + h];
  const float4* x4t = (const float4*)(x + (size_t)t * NN * 32) + f4;  // + s*8 per edge
  float4 acc = make_float4(0.f, 0.f, 0.f, 0.f);
  float den = 0.f;
  int beg = rowptr[n], end = rowptr[n + 1];
  // virtual list [beg, end]: edges then self-loop at position `end`
  int v = beg;
  for (; v + 3 <= end; v += 4) {
    int s0 = csr[v];                               // v..v+2 < end guaranteed (v+3 <= end)
    int s1 = csr[v + 1];
    int s2 = csr[v + 2];
    int s3 = (v + 3 < end) ? csr[v + 3] : n;
    float a0 = alst[(size_t)s0 * 8] + adv;
    float a1 = alst[(size_t)s1 * 8] + adv;
    float a2 = alst[(size_t)s2 * 8] + adv;
    float a3 = alst[(size_t)s3 * 8] + adv;
    float4 x0 = x4t[(size_t)s0 * 8];
    float4 x1 = x4t[(size_t)s1 * 8];
    float4 x2 = x4t[(size_t)s2 * 8];
    float4 x3 = x4t[(size_t)s3 * 8];
    a0 = fmaxf(a0, 0.2f * a0);
    a1 = fmaxf(a1, 0.2f * a1);
    a2 = fmaxf(a2, 0.2f * a2);
    a3 = fmaxf(a3, 0.2f * a3);
    float e0 = __expf(a0), e1 = __expf(a1), e2 = __expf(a2), e3 = __expf(a3);
    acc.x = fmaf(e0, x0.x, acc.x); acc.y = fmaf(e0, x0.y, acc.y);
    acc.z = fmaf(e0, x0.z, acc.z); acc.w = fmaf(e0, x0.w, acc.w);
    acc.x = fmaf(e1, x1.x, acc.x); acc.y = fmaf(e1, x1.y, acc.y);
    acc.z = fmaf(e1, x1.z, acc.z); acc.w = fmaf(e1, x1.w, acc.w);
    acc.x = fmaf(e2, x2.x, acc.x); acc.y = fmaf(e2, x2.y, acc.y);
    acc.z = fmaf(e2, x2.z, acc.z); acc.w = fmaf(e2, x2.w, acc.w);
    acc.x = fmaf(e3, x3.x, acc.x); acc.y = fmaf(e3, x3.y, acc.y);
    acc.z = fmaf(e3, x3.z, acc.z); acc.w = fmaf(e3, x3.w, acc.w);
    den += e0 + e1 + e2 + e3;
  }
  for (; v <= end; ++v) {                          // 0..3 leftovers (incl. self-loop)
    int s = (v < end) ? csr[v] : n;
    float a = alst[(size_t)s * 8] + adv;
    a = fmaxf(a, 0.2f * a);
    float e = __expf(a);
    float4 xv = x4t[(size_t)s * 8];
    acc.x = fmaf(e, xv.x, acc.x); acc.y = fmaf(e, xv.y, acc.y);
    acc.z = fmaf(e, xv.z, acc.z); acc.w = fmaf(e, xv.w, acc.w);
    den += e;
  }
  // aggx[t][n][h*32 + f4*4 .. +3] -- addr = base + lane*4 floats: fully coalesced
  ((float4*)(aggx + ((size_t)t * NN + n) * 256))[lane] = acc;
  if (f4 == 0) den1[((size_t)t * NN + n) * 8 + h] = den;
}

// ---------------- dense epilogue: 16-node tiles, 8 tiles/block, weights resident -----------
// launch_bounds(256,1): VGPR unconstrained (~112 used) so the 32 float4 of weights truly
// live in registers (round-8 proved per-thread weight STREAMING is 8x worse: 64KB/wave
// working set thrashes the 32KB L1 -> 1250us). PTILES=8: each block owns one 16-node group
// across ALL 8 t (tile=blk*8+it -> t=it, n0=blk*16) -- weight load amortized 8x, aggx/den1
// locality per block. Grid 1250.

#define PTILES 8

__global__ __launch_bounds__(256, 1) void k_post(const float* __restrict__ aggx,
    const float* __restrict__ den1, const float* __restrict__ W1T, const float* __restrict__ b1,
    const float* __restrict__ W2T, const float* __restrict__ as2, const float* __restrict__ ad2,
    float* __restrict__ h2, float* __restrict__ al2s, float* __restrict__ al2d) {
  __shared__ float aggs[16 * 256];   // phase-2 input; aliased as part[8][16][32] in phase 3
  __shared__ float rels[16 * 256];
  __shared__ float dens[16 * 8];     // INVERSE denominators
  float* part = aggs;                // 8*16*32 == 16*256 floats exactly
  int tid = threadIdx.x;

  int u = tid & 127, grp = tid >> 7;
  int j0 = 2 * u;
  int hj = j0 >> 5;
  // one-time per block: weights + biases into registers (amortized over PTILES tiles)
  float4 w1a[8], w1b[8];
  const float4* w1p = (const float4*)(W1T + j0 * 32);
  #pragma unroll
  for (int q8 = 0; q8 < 8; ++q8) { w1a[q8] = w1p[q8]; w1b[q8] = w1p[q8 + 8]; }
  float bj0 = b1[j0], bj1 = b1[j0 + 1];
  int q = u >> 4, fp = u & 15, f0 = 2 * fp;
  float4 w2a[8], w2b[8];
  const float4* w2pa = (const float4*)(W2T + f0 * 256 + q * 32);
  const float4* w2pb = (const float4*)(W2T + (f0 + 1) * 256 + q * 32);
  #pragma unroll
  for (int q8 = 0; q8 < 8; ++q8) { w2a[q8] = w2pa[q8]; w2b[q8] = w2pb[q8]; }
  float as2f = as2[tid & 31], ad2f = ad2[tid & 31];

  for (int it = 0; it < PTILES; ++it) {
    int tile = blockIdx.x * PTILES + it;
    int t = tile & 7;
    int n0 = (tile >> 3) * 16;

    if (it > 0) __syncthreads();     // part/dens reads of prev tile done before overwrite

    const float4* ag4 = (const float4*)(aggx + ((size_t)t * NN + n0) * 256);
    float4* as4 = (float4*)aggs;
    #pragma unroll
    for (int k = 0; k < 4; ++k) as4[tid + k * 256] = ag4[tid + k * 256];
    if (tid < 128) dens[tid] = 1.f / den1[((size_t)t * NN + n0) * 8 + tid];
    __syncthreads();

    // phase 2: rows grp*8..+7, columns j0, j0+1 (aggs reads shared by both columns)
    #pragma unroll
    for (int g = 0; g < 8; ++g) {
      int row = grp * 8 + g;
      const float4* ar4 = (const float4*)(aggs + row * 256 + hj * 32);
      float a0 = 0.f, a1 = 0.f;
      #pragma unroll
      for (int k4 = 0; k4 < 8; ++k4) {
        float4 av = ar4[k4];
        a0 = fmaf(av.x, w1a[k4].x, fmaf(av.y, w1a[k4].y,
             fmaf(av.z, w1a[k4].z, fmaf(av.w, w1a[k4].w, a0))));
        a1 = fmaf(av.x, w1b[k4].x, fmaf(av.y, w1b[k4].y,
             fmaf(av.z, w1b[k4].z, fmaf(av.w, w1b[k4].w, a1))));
      }
      float invd = dens[row * 8 + hj];
      float2 r;
      r.x = fmaxf(fmaf(a0, invd, bj0), 0.f);
      r.y = fmaxf(fmaf(a1, invd, bj1), 0.f);
      *(float2*)(rels + row * 256 + j0) = r;
    }
    __syncthreads();   // rels ready; aggs dead -> reuse as part

    // phase 3: q-split over K (8 chunks of 32), columns f0, f0+1
    #pragma unroll
    for (int g = 0; g < 8; ++g) {
      int row = grp * 8 + g;
      const float4* r4 = (const float4*)(rels + row * 256 + q * 32);
      float a0 = 0.f, a1 = 0.f;
      #pragma unroll
      for (int jj = 0; jj < 8; ++jj) {
        float4 a4 = r4[jj];
        a0 = fmaf(a4.x, w2a[jj].x, fmaf(a4.y, w2a[jj].y,
             fmaf(a4.z, w2a[jj].z, fmaf(a4.w, w2a[jj].w, a0))));
        a1 = fmaf(a4.x, w2b[jj].x, fmaf(a4.y, w2b[jj].y,
             fmaf(a4.z, w2b[jj].z, fmaf(a4.w, w2b[jj].w, a1))));
      }
      float2 pr; pr.x = a0; pr.y = a1;
      *(float2*)(part + q * 512 + row * 32 + f0) = pr;
    }
    __syncthreads();

    // reduce over q + h2 write + layer-2 logits
    #pragma unroll
    for (int rep = 0; rep < 2; ++rep) {
      int row = (tid >> 5) + rep * 8;
      int ff = tid & 31;
      float v = 0.f;
      #pragma unroll
      for (int qq = 0; qq < 8; ++qq) v += part[qq * 512 + row * 32 + ff];
      int nn = n0 + row;
      h2[((size_t)t * NN + nn) * CD + ff] = v;
      float vs = v * as2f, vd = v * ad2f;
      #pragma unroll
      for (int m = 1; m < 32; m <<= 1) {
        vs += __shfl_xor(vs, m, 64);
        vd += __shfl_xor(vd, m, 64);
      }
      if (ff == 0) {
        al2s[(size_t)t * NN + nn] = vs;
        al2d[(size_t)t * NN + nn] = vd;
      }
    }
  }
}

// ---------------- layer-2 aggregation, ALL t in one wave: lane=(t, f-quad), 2-edge unroll ---

__global__ __launch_bounds__(256, 4) void k_agg2(const float* __restrict__ h2,
    const float* __restrict__ al2s, const float* __restrict__ al2d,
    const int* __restrict__ rowptr, const int* __restrict__ csr,
    const float* __restrict__ b2, float* __restrict__ out) {
  int tid = threadIdx.x;
  int wv = tid >> 6, lane = tid & 63;
  int t = lane >> 3, p = lane & 7;
  int n = blockIdx.x * 4 + wv;
  const float* alst = al2s + (size_t)t * NN;
  float adv = al2d[(size_t)t * NN + n];
  const float4* h24 = (const float4*)h2 + (size_t)t * NN * 8 + p;
  float4 b4 = ((const float4*)b2)[p];
  float4 acc = make_float4(0.f, 0.f, 0.f, 0.f);
  float den = 0.f;
  int beg = rowptr[n], end = rowptr[n + 1];
  int v = beg;
  for (; v + 1 <= end; v += 2) {
    int s0 = csr[v];
    int s1 = (v + 1 < end) ? csr[v + 1] : n;
    float a0 = alst[s0] + adv;
    float a1 = alst[s1] + adv;
    float4 u = h24[(size_t)s0 * 8];
    float4 w = h24[(size_t)s1 * 8];
    a0 = fmaxf(a0, 0.2f * a0);
    a1 = fmaxf(a1, 0.2f * a1);
    float e0 = __expf(a0), e1 = __expf(a1);
    acc.x = fmaf(e1, w.x, fmaf(e0, u.x, acc.x));
    acc.y = fmaf(e1, w.y, fmaf(e0, u.y, acc.y));
    acc.z = fmaf(e1, w.z, fmaf(e0, u.z, acc.z));
    acc.w = fmaf(e1, w.w, fmaf(e0, u.w, acc.w));
    den += e0 + e1;
  }
  if (v <= end) {
    int s = (v < end) ? csr[v] : n;
    float a = alst[s] + adv;
    a = fmaxf(a, 0.2f * a);
    float e = __expf(a);
    float4 u = h24[(size_t)s * 8];
    acc.x = fmaf(e, u.x, acc.x);
    acc.y = fmaf(e, u.y, acc.y);
    acc.z = fmaf(e, u.z, acc.z);
    acc.w = fmaf(e, u.w, acc.w);
    den += e;
  }
  float inv = 1.f / den;
  float4 o;
  o.x = fmaf(acc.x, inv, b4.x);
  o.y = fmaf(acc.y, inv, b4.y);
  o.z = fmaf(acc.z, inv, b4.z);
  o.w = fmaf(acc.w, inv, b4.w);
  ((float4*)out)[((size_t)t * NN + n) * 8 + p] = o;
}

// ---------------- LSTM, all t in one kernel: weights in VGPRs, h/c in LDS ------------------

__global__ __launch_bounds__(256) void k_lstm_all(const float* __restrict__ agg2o,
    const float* __restrict__ w_ih, const float* __restrict__ w_hh,
    const float* __restrict__ b_ih, const float* __restrict__ b_hh,
    float* __restrict__ out) {
  __shared__ float xs[16 * 32], hs[16 * 32], cs[16 * 32], pre[16 * 128];
  int tid = threadIdx.x;
  int slot = tid >> 7;
  int r = tid & 127;
  float4 wi[8], wh[8];
  const float4* wi4 = (const float4*)(w_ih + r * 32);
  const float4* wh4 = (const float4*)(w_hh + r * 32);
  #pragma unroll
  for (int q = 0; q < 8; ++q) { wi[q] = wi4[q]; wh[q] = wh4[q]; }
  float bias = b_ih[r] + b_hh[r];
  int base = blockIdx.x * 16;
  for (int i = tid; i < 512; i += 256) { hs[i] = 0.f; cs[i] = 0.f; }
  for (int t = 0; t < TT; ++t) {
    for (int i = tid; i < 512; i += 256) xs[i] = agg2o[(size_t)t * NN * 32 + base * 32 + i];
    __syncthreads();
    #pragma unroll
    for (int g = 0; g < 8; ++g) {
      int nl = slot * 8 + g;
      const float4* xv4 = (const float4*)(xs + nl * 32);
      const float4* hv4 = (const float4*)(hs + nl * 32);
      float acc = bias;
      #pragma unroll
      for (int q = 0; q < 8; ++q) {
        float4 a = xv4[q], b = hv4[q];
        acc = fmaf(a.x, wi[q].x, acc);
        acc = fmaf(a.y, wi[q].y, acc);
        acc = fmaf(a.z, wi[q].z, acc);
        acc = fmaf(a.w, wi[q].w, acc);
        acc = fmaf(b.x, wh[q].x, acc);
        acc = fmaf(b.y, wh[q].y, acc);
        acc = fmaf(b.z, wh[q].z, acc);
        acc = fmaf(b.w, wh[q].w, acc);
      }
      pre[nl * 128 + r] = acc;
    }
    __syncthreads();
    for (int i = tid; i < 512; i += 256) {
      int nl = i >> 5, k = i & 31;
      float ai = pre[nl * 128 + k];
      float af = pre[nl * 128 + 32 + k];
      float ag = pre[nl * 128 + 64 + k];
      float ao = pre[nl * 128 + 96 + k];
      float ii = 1.f / (1.f + __expf(-ai));
      float ff = 1.f / (1.f + __expf(-af));
      float gg = tanhf(ag);
      float oo = 1.f / (1.f + __expf(-ao));
      float cn = fmaf(ff, cs[i], ii * gg);
      float hn = oo * tanhf(cn);
      cs[i] = cn; hs[i] = hn;
      out[(size_t)t * NN * 32 + base * 32 + i] = hn;
    }
  }
}

// ---------------- softmax over nodes, coalesced two-pass ----------------

__global__ __launch_bounds__(256) void k_sm_sum(const float* __restrict__ out, float* __restrict__ sums) {
  int t = blockIdx.y;
  const float4* b4 = (const float4*)(out + ((size_t)t * NN + blockIdx.x * 800) * CD);
  int tid = threadIdx.x;
  float4 s4 = make_float4(0.f, 0.f, 0.f, 0.f);
  for (int i = tid; i < 6400; i += 256) {
    float4 v = b4[i];
    s4.x += __expf(v.x); s4.y += __expf(v.y);
    s4.z += __expf(v.z); s4.w += __expf(v.w);
  }
  __shared__ float4 red[256];
  red[tid] = s4;
  __syncthreads();
  for (int off = 128; off >= 8; off >>= 1) {
    if (tid < off) {
      float4 o = red[tid + off];
      red[tid].x += o.x; red[tid].y += o.y; red[tid].z += o.z; red[tid].w += o.w;
    }
    __syncthreads();
  }
  if (tid < 8) {
    float4 v = red[tid];
    int c0 = tid * 4;
    atomicAdd(&sums[t * CD + c0 + 0], v.x);
    atomicAdd(&sums[t * CD + c0 + 1], v.y);
    atomicAdd(&sums[t * CD + c0 + 2], v.z);
    atomicAdd(&sums[t * CD + c0 + 3], v.w);
  }
}

__global__ __launch_bounds__(256) void k_sm_scale(float* __restrict__ out, const float* __restrict__ sums) {
  int t = blockIdx.y;
  __shared__ float inv[CD];
  int tid = threadIdx.x;
  if (tid < CD) inv[tid] = 1.f / sums[t * CD + tid];
  __syncthreads();
  float4* b4 = (float4*)(out + ((size_t)t * NN + blockIdx.x * 800) * CD);
  for (int i = tid; i < 6400; i += 256) {
    float4 v = b4[i];
    int c0 = (4 * i) & 31;
    v.x = __expf(v.x) * inv[c0];
    v.y = __expf(v.y) * inv[c0 + 1];
    v.z = __expf(v.z) * inv[c0 + 2];
    v.w = __expf(v.w) * inv[c0 + 3];
    b4[i] = v;
  }
}

// ---------------- launch ----------------

extern "C" void kernel_launch(void* const* d_in, const int* in_sizes, int n_in,
                              void* d_out, int out_size, void* d_ws, size_t ws_size,
                              hipStream_t stream) {
  const float* x   = (const float*)d_in[0];
  const float* W1  = (const float*)d_in[1];
  const float* as1 = (const float*)d_in[2];
  const float* ad1 = (const float*)d_in[3];
  const float* b1  = (const float*)d_in[4];
  const float* W2  = (const float*)d_in[5];
  const float* as2 = (const float*)d_in[6];
  const float* ad2 = (const float*)d_in[7];
  const float* b2  = (const float*)d_in[8];
  const float* wih = (const float*)d_in[9];
  const float* whh = (const float*)d_in[10];
  const float* bih = (const float*)d_in[11];
  const float* bhh = (const float*)d_in[12];
  const int*   ei  = (const int*)d_in[13];
  const int* srcp = ei;
  const int* dstp = ei + NE;
  float* out = (float*)d_out;

  float* ws = (float*)d_ws;
  float* aggx  = ws;  ws += (size_t)TT * NN * 256;   // 164 MB
  float* den1  = ws;  ws += (size_t)TT * NN * 8;
  float* al1s  = ws;  ws += (size_t)TT * NN * 8;
  float* al1d  = ws;  ws += (size_t)TT * NN * 8;
  float* h2    = ws;  ws += (size_t)TT * NN * CD;
  float* al2s  = ws;  ws += (size_t)TT * NN;
  float* al2d  = ws;  ws += (size_t)TT * NN;
  float* agg2o = ws;  ws += (size_t)TT * NN * CD;
  float* sums  = ws;  ws += TT * CD;
  float* wsrc  = ws;  ws += 256;
  float* wdst  = ws;  ws += 256;
  float* W1T   = ws;  ws += D1 * 32;
  float* W2T   = ws;  ws += 32 * D1;
  int* rowptr = (int*)ws;
  int* fill   = rowptr + NN + 1;
  int* csr    = fill + NN;
  int* deg    = csr + NE;

  hipMemsetAsync(sums, 0, TT * CD * sizeof(float), stream);
  hipMemsetAsync(deg, 0, NN * sizeof(int), stream);

  k_deg<<<(NE + 255) / 256, 256, 0, stream>>>(dstp, deg);
  k_scan<<<1, 1024, 0, stream>>>(deg, rowptr, fill);
  k_fill<<<(NE + 255) / 256, 256, 0, stream>>>(srcp, dstp, fill, csr);
  k_prew<<<1, 256, 0, stream>>>(W1, as1, ad1, W2, wsrc, wdst, W1T, W2T);

  k_logits8<<<(NN / 32) * TT, 256, 0, stream>>>(x, wsrc, wdst, al1s, al1d);
  k_gat1<<<(NN / 4) * TT, 256, 0, stream>>>(x, al1s, al1d, rowptr, csr, aggx, den1);
  k_post<<<(NN / 16) * TT / PTILES, 256, 0, stream>>>(aggx, den1, W1T, b1, W2T, as2, ad2,
                                                      h2, al2s, al2d);
  k_agg2<<<NN / 4, 256, 0, stream>>>(h2, al2s, al2d, rowptr, csr, b2, agg2o);
  k_lstm_all<<<NN / 16, 256, 0, stream>>>(agg2o, wih, whh, bih, bhh, out);

  k_sm_sum<<<dim3(25, TT), 256, 0, stream>>>(out, sums);
  k_sm_scale<<<dim3(25, TT), 256, 0, stream>>>(out, sums);
}